// Round 10
// baseline (1045.380 us; speedup 1.0000x reference)
//
#include <hip/hip_runtime.h>

constexpr int TT = 512;    // timesteps
constexpr int BB = 256;    // batch
constexpr int HH = 128;    // hidden = embed
constexpr int VV = 32000;  // vocab

typedef _Float16 h2 __attribute__((ext_vector_type(2)));
typedef _Float16 f16x4 __attribute__((ext_vector_type(4)));
typedef _Float16 f16x8 __attribute__((ext_vector_type(8)));
typedef float f32x4 __attribute__((ext_vector_type(4)));

struct __align__(16) H2x4 { h2 a, b, c, d; };

__device__ __forceinline__ h2 pkrtz(float a, float b) {
  return __builtin_bit_cast(h2, __builtin_amdgcn_cvt_pkrtz(a, b));
}
__device__ __forceinline__ float fsigmoid(float x) {
  return 1.f / (1.f + __expf(-x));
}
__device__ __forceinline__ float ftanh(float x) {
  return 1.f - 2.f / (__expf(2.f * x) + 1.f);
}

// One block per batch element (256 blocks = 256 CUs), 512 threads = 8 waves.
// MFMA recurrence with weights resident in the ACC half of the unified RF:
// the f16 weight set (512 KB) fills the whole CU register file, so the
// allocator must use AGPRs — v_dot2 can't read them (R1-R9's measured 2.4x
// copy storm) but MFMA can. Batch dim is broadcast (B cols all equal, 16x
// redundant MACs) to keep all 256 CUs busy with 1 batch row each.
//   wave w owns units [16w,16w+16): A-frags wfrag[g][kt] (g=gate, kt=k/32),
//   n-tile = g*128+16w, A[m=lane&15][k=quad*8+j] -> 32 frags = 128 regs.
//   B-frag: comb[kt*32+quad*8 ..+8) broadcast to all cols (1 b128/kt).
//   D: row=quad*4+r = unit offset, col=lane&15 (all equal) -> all 4 gates of
//   unit u0+r land in every lane of the quad; in-lane activation + c-state;
//   col-0 lanes write h (b64) to the double-buffered comb. 1 barrier/step.
//   e_{t+1}: waves 0-1 load emb (global, hidden behind MFMA+act) and write
//   comb[buf^1][0..128).
__global__ __launch_bounds__(512, 2) void lstm_rec(
    const int* __restrict__ x, const float* __restrict__ emb,
    const float* __restrict__ Wi, const float* __restrict__ bi,
    const float* __restrict__ Wf, const float* __restrict__ bf,
    const float* __restrict__ Wc, const float* __restrict__ bc,
    const float* __restrict__ Wo, const float* __restrict__ bo,
    _Float16* __restrict__ hbf) {
  const int b = blockIdx.x;
  const int tid = threadIdx.x;
  const int w = tid >> 6;      // wave = unit group
  const int lane = tid & 63;
  const int m16 = lane & 15;   // A row / D col
  const int quad = lane >> 4;

  __shared__ int xrow[TT];
  __shared__ __align__(16) _Float16 comb[2][256];  // [buf][ e(128) | h(128) ]

  xrow[tid] = x[b * TT + tid];

  // ---- A-operand weight fragments: wfrag[g][kt][j] = Wg[kt*32+quad*8+j][16w+m16]
  const float* Wp[4] = {Wi, Wf, Wc, Wo};
  const int ncol = 16 * w + m16;
  f16x8 wfrag[4][8];
#pragma unroll
  for (int g = 0; g < 4; ++g) {
    const float* Wg = Wp[g];
#pragma unroll
    for (int kt = 0; kt < 8; ++kt) {
      const float* base = Wg + (size_t)(kt * 32 + quad * 8) * HH + ncol;
      f16x8 v;
#pragma unroll
      for (int j = 0; j < 8; ++j) v[j] = (_Float16)base[j * HH];
      wfrag[g][kt] = v;
    }
  }

  // this lane's 4 units u = u0 + r (same for every col lane in the quad)
  const int u0 = 16 * w + 4 * quad;
  float bia[4], bif_[4], bic[4], bio[4], cst[4];
#pragma unroll
  for (int r = 0; r < 4; ++r) {
    bia[r] = bi[u0 + r]; bif_[r] = bf[u0 + r];
    bic[r] = bc[u0 + r]; bio[r] = bo[u0 + r];
    cst[r] = 0.f;
  }

  const bool el = (tid < 128);  // waves 0-1: e loaders

  __syncthreads();  // xrow visible

  // init comb[0] = [ e_0 | 0 ]
  if (el) {
    comb[0][tid] = (_Float16)emb[(size_t)xrow[0] * HH + tid];
    comb[0][128 + tid] = (_Float16)0.f;
  }
  __syncthreads();

  int buf = 0;
  for (int t = 0; t < TT; ++t) {
    // B fragments: broadcast comb (4 distinct addrs/wave, all 16B aligned)
    f16x8 bfrag[8];
    const _Float16* cb = &comb[buf][quad * 8];
#pragma unroll
    for (int kt = 0; kt < 8; ++kt) bfrag[kt] = *(const f16x8*)(cb + kt * 32);

    // e_{t+1} global load issued early (emb is L3-resident; ~700 cyc to hide)
    float e_nf = 0.f;
    if (el) {
      const int tn = (t + 1 < TT) ? t + 1 : TT - 1;
      e_nf = emb[(size_t)xrow[tn] * HH + tid];
    }

    // 32 MFMA: acc[g] += wfrag[g][kt] * bfrag[kt]
    f32x4 acc[4] = {{0, 0, 0, 0}, {0, 0, 0, 0}, {0, 0, 0, 0}, {0, 0, 0, 0}};
#pragma unroll
    for (int kt = 0; kt < 8; ++kt) {
#pragma unroll
      for (int g = 0; g < 4; ++g)
        acc[g] = __builtin_amdgcn_mfma_f32_16x16x32_f16(wfrag[g][kt], bfrag[kt],
                                                        acc[g], 0, 0, 0);
    }

    // in-lane activation + state update (all col lanes redundantly)
    f16x4 hv;
#pragma unroll
    for (int r = 0; r < 4; ++r) {
      const float gi = fsigmoid(acc[0][r] + bia[r]);
      const float gf = fsigmoid(acc[1][r] + bif_[r]);
      const float gc = ftanh(acc[2][r] + bic[r]);
      const float go = fsigmoid(acc[3][r] + bio[r]);
      cst[r] = gf * cst[r] + gi * gc;
      hv[r] = (_Float16)(go * ftanh(cst[r]));
    }

    // col-0 lanes write h; e-loaders write e_{t+1}
    if (m16 == 0) *(f16x4*)(&comb[buf ^ 1][128 + u0]) = hv;
    if (el) comb[buf ^ 1][tid] = (_Float16)e_nf;
    if (t == TT - 1 && m16 == 0)
      *(f16x4*)(hbf + (size_t)b * HH + u0) = hv;

    __syncthreads();
    buf ^= 1;
  }
}

// Wout[k][v] fp32 -> Wt[v][k] fp16 (coalesced loads across lanes=v).
__global__ __launch_bounds__(256, 4) void wout_tr(const float* __restrict__ Wout,
                                                  _Float16* __restrict__ Wt) {
  const int v = blockIdx.x * 256 + threadIdx.x;
#pragma unroll 1
  for (int kc = 0; kc < 16; ++kc) {
    float f[8];
#pragma unroll
    for (int i = 0; i < 8; ++i) f[i] = Wout[(size_t)(kc * 8 + i) * VV + v];
    H2x4 q;
    q.a = pkrtz(f[0], f[1]);
    q.b = pkrtz(f[2], f[3]);
    q.c = pkrtz(f[4], f[5]);
    q.d = pkrtz(f[6], f[7]);
    *(H2x4*)(Wt + (size_t)v * HH + kc * 8) = q;
  }
}

// logits = h @ Wout + bout via f16 MFMA, register-only.
// Block: 4 waves; tile [64 bat x 128 v]; wave: [64 bat x 32 v].
__global__ __launch_bounds__(256, 4) void lstm_out(
    const _Float16* __restrict__ Wt, const _Float16* __restrict__ hbf,
    const float* __restrict__ bout, float* __restrict__ out) {
  const int tid = threadIdx.x;
  const int wv = tid >> 6;
  const int lane = tid & 63;
  const int vblk = blockIdx.x % 250;
  const int batblk = blockIdx.x / 250;
  const int n16 = lane & 15;
  const int quad = lane >> 4;
  const int vbase = vblk * 128 + wv * 32;
  const int batbase = batblk * 64;

  f32x4 acc[4][2] = {};
#pragma unroll
  for (int ks = 0; ks < 4; ++ks) {
    const int k = ks * 32 + quad * 8;
    f16x8 a[4], bf_[2];
#pragma unroll
    for (int mt = 0; mt < 4; ++mt)
      a[mt] = *(const f16x8*)(hbf + (size_t)(batbase + mt * 16 + n16) * HH + k);
#pragma unroll
    for (int vt = 0; vt < 2; ++vt)
      bf_[vt] = *(const f16x8*)(Wt + (size_t)(vbase + vt * 16 + n16) * HH + k);
#pragma unroll
    for (int mt = 0; mt < 4; ++mt)
#pragma unroll
      for (int vt = 0; vt < 2; ++vt)
        acc[mt][vt] = __builtin_amdgcn_mfma_f32_16x16x32_f16(a[mt], bf_[vt],
                                                             acc[mt][vt], 0, 0, 0);
  }
#pragma unroll
  for (int vt = 0; vt < 2; ++vt) {
    const int v = vbase + vt * 16 + n16;
    const float bv = bout[v];
#pragma unroll
    for (int mt = 0; mt < 4; ++mt) {
#pragma unroll
      for (int r = 0; r < 4; ++r) {
        const int bat = batbase + mt * 16 + quad * 4 + r;
        out[(size_t)bat * VV + v] = acc[mt][vt][r] + bv;
      }
    }
  }
}

extern "C" void kernel_launch(void* const* d_in, const int* in_sizes, int n_in,
                              void* d_out, int out_size, void* d_ws,
                              size_t ws_size, hipStream_t stream) {
  const int* x = (const int*)d_in[0];
  const float* emb = (const float*)d_in[1];
  const float* Wi = (const float*)d_in[2];
  const float* bi = (const float*)d_in[3];
  const float* Wf = (const float*)d_in[4];
  const float* bf = (const float*)d_in[5];
  const float* Wc = (const float*)d_in[6];
  const float* bc = (const float*)d_in[7];
  const float* Wo = (const float*)d_in[8];
  const float* bo = (const float*)d_in[9];
  const float* Wout = (const float*)d_in[10];
  const float* bout = (const float*)d_in[11];
  float* out = (float*)d_out;

  _Float16* Wt = (_Float16*)d_ws;        // 32000*128 f16 = 8.192 MB
  _Float16* hbf = Wt + (size_t)VV * HH;  // 256*128 f16 = 64 KB

  wout_tr<<<VV / 256, 256, 0, stream>>>(Wout, Wt);
  lstm_rec<<<BB, 512, 0, stream>>>(x, emb, Wi, bi, Wf, bf, Wc, bc, Wo, bo, hbf);
  lstm_out<<<(VV / 128) * (BB / 64), 256, 0, stream>>>(Wt, hbf, bout, out);
}